// Round 17
// baseline (175.058 us; speedup 1.0000x reference)
//
#include <hip/hip_runtime.h>
#include <hip/hip_bf16.h>

// Swin block fully fused, bf16 MFMA. B=64, H=W=56, C=96, nh=3, d=32, WS=7, SS=3, N=49, nW=64.
// Round 17: round-15 base + (1) proj weights prefetched to VGPRs during attention and
// ds_written to buf0 (removes the one exposed global->LDS stage), (2) XCD-aware block swizzle.
typedef __attribute__((ext_vector_type(8))) short short8;  // 8 bf16 = one A/B frag
typedef __attribute__((ext_vector_type(4))) float f32x4;   // C/D frag

constexpr int HW = 56;

// ---- LDS pool (bf16 elements). Frag-read bases 16B-aligned. ----
constexpr int SR    = 104;             // row stride for [64][96] token-major buffers
constexpr int SVT   = 200;             // row stride for vT [32][3*64]
constexpr int OFF_X = 0;               // [64][SR]: xln -> P (own row) -> buf1 sets 0..12
constexpr int OFF_Q = 64 * SR;         // [64][SR]: q -> attn-out -> yn -> h (all own row)
constexpr int OFF_K = 2 * 64 * SR;     // [64][SR]: k ; after attention: buf0
constexpr int OFF_V = 3 * 64 * SR;     // [32][SVT]: v^T ; tail of buf0 + buf1 sets 13..17
constexpr int POOLN = OFF_V + 32 * SVT;  // 26368 shorts = 52736 B -> 3 blocks/CU
// post-attention weight buffers (set = 512 shorts):
//   buf0: sets 0..17 at OFF_K + s*512
//   buf1: sets 0..12 at s*512 (X region); sets 13..17 at 22528 + (s-13)*512

// ---- d_ws layout: bf16 weights frag-major [set*512 + lane*8 + j], then f32 bias planes ----
constexpr int WQKV  = 0;               // 18 tiles; Q tiles pre-scaled by d^-0.5
constexpr int WPROJ = 27648;           // 18 sets (one 18KB chunk)
constexpr int WFC1  = 36864;           // chunk-major: chunk cn = sets cn*18 .. cn*18+17
constexpr int WFC2  = 73728;           // chunk-major
constexpr int WTOT  = 110592;          // *2B = 221184 bytes
constexpr int BIASN = 64 * 3 * 49 * 64;           // f32 elements
constexpr size_t WS_M1 = (size_t)WTOT * 2;        // weights only
constexpr size_t WS_M2 = WS_M1 + (size_t)BIASN * 4;  // + bias planes

__device__ __forceinline__ ushort bfc(float f) {
  union { __hip_bfloat16 h; ushort u; } v;
  v.h = __float2bfloat16(f);
  return v.u;
}
__device__ __forceinline__ uint pk2(float a, float b) {
  union { __hip_bfloat162 h2; uint u; } v;
  v.h2 = __float22bfloat162_rn(make_float2(a, b));
  return v.u;
}
__device__ __forceinline__ void st4(short* p, float a, float b, float c, float d) {
  uint2 u; u.x = pk2(a, b); u.y = pk2(c, d);
  *(uint2*)p = u;
}
__device__ __forceinline__ short8 ldw8(const float* p) {
  float4 a = *(const float4*)p;
  float4 b = *(const float4*)(p + 4);
  short8 r;
  r[0] = (short)bfc(a.x); r[1] = (short)bfc(a.y); r[2] = (short)bfc(a.z); r[3] = (short)bfc(a.w);
  r[4] = (short)bfc(b.x); r[5] = (short)bfc(b.y); r[6] = (short)bfc(b.z); r[7] = (short)bfc(b.w);
  return r;
}
template<bool PRE>
__device__ __forceinline__ short8 wfrag(const short* wsb, int ts, int lane, const float* fsrc) {
  if constexpr (PRE) return *(const short8*)&wsb[(ts << 9) + lane * 8];
  else               return ldw8(fsrc);
}
// GELU sigmoid form with fast rcp: x * sigma(1.702 x)
__device__ __forceinline__ float gelu(float v) {
  return v * __builtin_amdgcn_rcpf(1.0f + __expf(-1.702f * v));
}
// buffer set bases
__device__ __forceinline__ short* b0set(short* pool, int s) {
  return pool + OFF_K + (s << 9);
}
__device__ __forceinline__ short* b1set(short* pool, int s) {
  return pool + (s < 13 ? (s << 9) : 22528 + ((s - 13) << 9));
}
// stage one 18KB chunk (18 sets) global->LDS, wave-split; B selects buf0/buf1
template<bool B1>
__device__ __forceinline__ void stage18(const short* g0, short* pool, int wv, int lane) {
  #pragma unroll
  for (int i = 0; i < 5; ++i) {
    int s = wv + 4 * i;
    if (s < 18) {
      short* dst = B1 ? b1set(pool, s) : b0set(pool, s);
      __builtin_amdgcn_global_load_lds((const unsigned int*)(g0 + (s << 9) + lane * 8),
                                       (unsigned int*)dst, 16, 0, 0);
    }
  }
}

// one-shot weight conversion f32 -> bf16, frag-major; Q tiles pre-scaled by d^-0.5
__global__ __launch_bounds__(256) void cvt_weights(
    const float* __restrict__ qkv_w, const float* __restrict__ proj_w,
    const float* __restrict__ fc1_w, const float* __restrict__ fc2_w,
    short* __restrict__ ws)
{
  int idx = blockIdx.x * 256 + threadIdx.x;
  if (idx >= WTOT) return;
  int j = idx & 7, lane = (idx >> 3) & 63;
  int cl = lane & 15;
  int g  = 8 * (lane >> 4) + j;
  float v;
  if (idx < WPROJ) {
    int ts = idx >> 9; int tile = ts / 3, s = ts - 3 * tile;
    v = qkv_w[(size_t)(16 * tile + cl) * 96 + 32 * s + g];
    if (tile < 6) v *= 0.17677669529663687f;   // fold Q scale
  } else if (idx < WFC1) {
    int ts = (idx - WPROJ) >> 9; int tile = ts / 3, s = ts - 3 * tile;
    v = proj_w[(size_t)(16 * tile + cl) * 96 + 32 * s + g];
  } else if (idx < WFC2) {
    int ts = (idx - WFC1) >> 9; int T = ts / 3, s = ts - 3 * T;
    int cn = T / 6, nt = T - 6 * cn;
    v = fc1_w[(size_t)(96 * cn + 16 * nt + cl) * 96 + 32 * s + g];
  } else {
    int ts = (idx - WFC2) >> 9; int T = ts / 3, s = ts - 3 * T;
    int cn = T / 6, nt = T - 6 * cn;
    v = fc2_w[(size_t)(16 * nt + cl) * 384 + 96 * cn + 32 * s + g];
  }
  ws[idx] = (short)bfc(v);
}

// one-shot fused bias planes: bias3[widx][h][q][64] = rel_bias + mask (k>=49 -> -1e30)
__global__ __launch_bounds__(256) void prep_bias(
    const float* __restrict__ attn_mask, const int* __restrict__ rel_index,
    const float* __restrict__ rel_tab, float* __restrict__ bias3)
{
  int idx = blockIdx.x * 256 + threadIdx.x;
  if (idx >= BIASN) return;
  int k = idx & 63;
  int t = idx >> 6;             // (widx*3 + h)*49 + q
  int q = t % 49;
  int wh = t / 49;
  int h = wh % 3, w = wh / 3;
  float v = -1e30f;
  if (k < 49) {
    int qk = q * 49 + k;
    v = rel_tab[rel_index[qk] * 3 + h] + attn_mask[(size_t)w * 2401 + qk];
  }
  bias3[idx] = v;
}

template<int MODE>   // 0: no ws; 1: +bf16 weights; 2: +bias planes
__global__ __launch_bounds__(256, 3) void swin_mfma_kernel(
    const float* __restrict__ x,          // [B,3136,96]
    const float* __restrict__ attn_mask,  // [64,49,49]
    const int*   __restrict__ rel_index,  // [2401]
    const float* __restrict__ n1g, const float* __restrict__ n1b,
    const float* __restrict__ qkv_w, const float* __restrict__ qkv_b,
    const float* __restrict__ rel_tab,    // [169,3]
    const float* __restrict__ proj_w, const float* __restrict__ proj_b,
    const float* __restrict__ n2g, const float* __restrict__ n2b,
    const float* __restrict__ fc1_w, const float* __restrict__ fc1_b,
    const float* __restrict__ fc2_w, const float* __restrict__ fc2_b,
    const short* __restrict__ wsw,
    const float* __restrict__ bias3,
    float* __restrict__ out)              // [B,3136,96]
{
  constexpr bool PRE = (MODE >= 1);
  __shared__ alignas(16) short pool[POOLN];

  const int tid  = threadIdx.x;
  const int wv   = tid >> 6;
  const int lane = tid & 63;
  const int ln   = lane & 15;
  const int gq   = lane >> 4;
  // XCD-aware swizzle: contiguous logical blocks per XCD (nwg % 8 == 0 -> bijective)
  const int nwg  = gridDim.x;
  const int braw = blockIdx.x;
  const int bw   = (braw & 7) * (nwg >> 3) + (braw >> 3);
  const int b    = bw >> 6, widx = bw & 63;
  const int wr   = widx >> 3, wc = widx & 7;

  const f32x4 zf = {0.f, 0.f, 0.f, 0.f};
  const int qq = 16 * wv + ln;        // this thread's token row

  auto gbase = [&](int n) -> size_t {
    int i = n / 7, j = n - 7 * i;
    int h = wr * 7 + i + 3; if (h >= HW) h -= HW;   // roll(-3)
    int w = wc * 7 + j + 3; if (w >= HW) w -= HW;
    return ((size_t)b * (HW * HW) + (size_t)h * HW + w) * 96;
  };
  const size_t obase = gbase(qq < 49 ? qq : 48);

  // ---- stage 1: token-per-thread-column load + LN1 -> xln; raw x kept in VGPRs ----
  float xraw[6][4];
  {
    if (qq < 49) {
      const float* xr = x + obase;
      #pragma unroll
      for (int nt = 0; nt < 6; ++nt) {
        float4 v = *(const float4*)&xr[16 * nt + 4 * gq];
        xraw[nt][0] = v.x; xraw[nt][1] = v.y; xraw[nt][2] = v.z; xraw[nt][3] = v.w;
      }
    } else {
      #pragma unroll
      for (int nt = 0; nt < 6; ++nt)
        xraw[nt][0] = xraw[nt][1] = xraw[nt][2] = xraw[nt][3] = 0.f;
    }
    float s1 = 0.f, s2 = 0.f;
    #pragma unroll
    for (int nt = 0; nt < 6; ++nt)
      #pragma unroll
      for (int r = 0; r < 4; ++r) { s1 += xraw[nt][r]; s2 += xraw[nt][r] * xraw[nt][r]; }
    s1 += __shfl_xor(s1, 16, 64); s1 += __shfl_xor(s1, 32, 64);
    s2 += __shfl_xor(s2, 16, 64); s2 += __shfl_xor(s2, 32, 64);
    float mean = s1 * (1.f / 96.f);
    float inv  = rsqrtf(s2 * (1.f / 96.f) - mean * mean + 1e-5f);
    #pragma unroll
    for (int nt = 0; nt < 6; ++nt) {
      float4 g4 = *(const float4*)&n1g[16 * nt + 4 * gq];
      float4 b4 = *(const float4*)&n1b[16 * nt + 4 * gq];
      st4(&pool[OFF_X + qq * SR + 16 * nt + 4 * gq],
          (xraw[nt][0] - mean) * inv * g4.x + b4.x,
          (xraw[nt][1] - mean) * inv * g4.y + b4.y,
          (xraw[nt][2] - mean) * inv * g4.z + b4.z,
          (xraw[nt][3] - mean) * inv * g4.w + b4.w);
    }
  }
  __syncthreads();

  // ---- stage 2: QKV. Q/K channel-rows; V transposed token-rows. N-split across waves ----
  {
    short8 af[3][4];
    #pragma unroll
    for (int s = 0; s < 3; ++s)
      #pragma unroll
      for (int m = 0; m < 4; ++m)
        af[s][m] = *(const short8*)&pool[OFF_X + (16 * m + ln) * SR + 32 * s + 8 * gq];

    const float sc_ = 0.17677669529663687f;
    for (int t = wv; t < 18; t += 4) {
      short8 wf[3];
      #pragma unroll
      for (int s = 0; s < 3; ++s)
        wf[s] = wfrag<PRE>(wsw + WQKV, t * 3 + s, lane,
                           qkv_w + (size_t)(16 * t + ln) * 96 + 32 * s + 8 * gq);
      int which = t / 6;               // 0=q 1=k 2=v
      if (which == 2) {
        int d  = 16 * (t - 12) + ln;
        float bv = qkv_b[192 + d];
        int dd = d & 31, hh = d >> 5;
        __builtin_amdgcn_s_setprio(1);
        #pragma unroll
        for (int m = 0; m < 4; ++m) {
          f32x4 acc = zf;
          #pragma unroll
          for (int s = 0; s < 3; ++s)
            acc = __builtin_amdgcn_mfma_f32_16x16x32_bf16(af[s][m], wf[s], acc, 0, 0, 0);
          st4(&pool[OFF_V + dd * SVT + hh * 64 + 16 * m + 4 * gq],
              acc[0] + bv, acc[1] + bv, acc[2] + bv, acc[3] + bv);
        }
        __builtin_amdgcn_s_setprio(0);
      } else {
        float4 b4 = *(const float4*)&qkv_b[16 * t + 4 * gq];
        if (which == 0) {
          if constexpr (PRE) { b4.x *= sc_; b4.y *= sc_; b4.z *= sc_; b4.w *= sc_; }
        }
        __builtin_amdgcn_s_setprio(1);
        #pragma unroll
        for (int m = 0; m < 4; ++m) {
          f32x4 acc = zf;
          #pragma unroll
          for (int s = 0; s < 3; ++s)
            acc = __builtin_amdgcn_mfma_f32_16x16x32_bf16(wf[s], af[s][m], acc, 0, 0, 0);
          int tok = 16 * m + ln;
          float v0 = acc[0] + b4.x, v1 = acc[1] + b4.y, v2 = acc[2] + b4.z, v3 = acc[3] + b4.w;
          if (which == 0) {
            if constexpr (PRE)
              st4(&pool[OFF_Q + tok * SR + 16 * t + 4 * gq], v0, v1, v2, v3);
            else
              st4(&pool[OFF_Q + tok * SR + 16 * t + 4 * gq], v0 * sc_, v1 * sc_, v2 * sc_, v3 * sc_);
          } else {
            st4(&pool[OFF_K + tok * SR + 16 * (t - 6) + 4 * gq], v0, v1, v2, v3);
          }
        }
        __builtin_amdgcn_s_setprio(0);
      }
    }
  }
  __syncthreads();

  // ---- T14: prefetch this wave's proj sets into VGPRs (latency hides under attention) ----
  uint4 pjreg[5];
  if constexpr (PRE) {
    #pragma unroll
    for (int i = 0; i < 5; ++i) {
      int s = wv + 4 * i;
      if (s < 18)
        pjreg[i] = *(const uint4*)(wsw + WPROJ + (s << 9) + lane * 8);
    }
  }

  // ---- stage 3: attention, per-head (bias+mask via C-in, no-max-sub softmax, rcp) ----
  const int qc = qq < 49 ? qq : 48;
  int   relvv[4][4];
  float maskb[4][4];
  if constexpr (MODE < 2) {
    #pragma unroll
    for (int nt = 0; nt < 4; ++nt)
      #pragma unroll
      for (int r = 0; r < 4; ++r) {
        int key = 16 * nt + 4 * gq + r;
        if (key < 49) {
          int qk = qc * 49 + key;
          relvv[nt][r] = rel_index[qk];
          maskb[nt][r] = attn_mask[(size_t)widx * 2401 + qk];
        } else {
          relvv[nt][r] = 0;
          maskb[nt][r] = -1e30f;
        }
      }
  }
  const float* bph = nullptr;
  if constexpr (MODE == 2) bph = bias3 + ((size_t)widx * 3 * 49 + qc) * 64;

  for (int h = 0; h < 3; ++h) {
    short8 bq = *(const short8*)&pool[OFF_Q + qq * SR + h * 32 + 8 * gq];
    f32x4 sc[4];
    __builtin_amdgcn_s_setprio(1);
    #pragma unroll
    for (int nt = 0; nt < 4; ++nt) {
      f32x4 bia;
      if constexpr (MODE == 2) {
        bia = *(const f32x4*)&bph[h * 3136 + 16 * nt + 4 * gq];
      } else {
        #pragma unroll
        for (int r = 0; r < 4; ++r)
          bia[r] = rel_tab[relvv[nt][r] * 3 + h] + maskb[nt][r];
      }
      short8 ak = *(const short8*)&pool[OFF_K + (16 * nt + ln) * SR + h * 32 + 8 * gq];
      sc[nt] = __builtin_amdgcn_mfma_f32_16x16x32_bf16(ak, bq, bia, 0, 0, 0);
    }
    __builtin_amdgcn_s_setprio(0);
    float pv[4][4];
    float sum = 0.f;
    #pragma unroll
    for (int nt = 0; nt < 4; ++nt)
      #pragma unroll
      for (int r = 0; r < 4; ++r) { pv[nt][r] = __expf(sc[nt][r]); sum += pv[nt][r]; }
    sum += __shfl_xor(sum, 16, 64);
    sum += __shfl_xor(sum, 32, 64);
    float inv = __builtin_amdgcn_rcpf(sum);
    #pragma unroll
    for (int nt = 0; nt < 4; ++nt)
      st4(&pool[OFF_X + qq * SR + 16 * nt + 4 * gq],
          pv[nt][0] * inv, pv[nt][1] * inv, pv[nt][2] * inv, pv[nt][3] * inv);

    short8 bp0 = *(const short8*)&pool[OFF_X + qq * SR + 8 * gq];
    short8 bp1 = *(const short8*)&pool[OFF_X + qq * SR + 32 + 8 * gq];
    __builtin_amdgcn_s_setprio(1);
    #pragma unroll
    for (int dt = 0; dt < 2; ++dt) {
      short8 av0 = *(const short8*)&pool[OFF_V + (16 * dt + ln) * SVT + h * 64 + 8 * gq];
      short8 av1 = *(const short8*)&pool[OFF_V + (16 * dt + ln) * SVT + h * 64 + 32 + 8 * gq];
      f32x4 o = __builtin_amdgcn_mfma_f32_16x16x32_bf16(av0, bp0, zf, 0, 0, 0);
      o = __builtin_amdgcn_mfma_f32_16x16x32_bf16(av1, bp1, o, 0, 0, 0);
      st4(&pool[OFF_Q + qq * SR + h * 32 + 16 * dt + 4 * gq], o[0], o[1], o[2], o[3]);
    }
    __builtin_amdgcn_s_setprio(0);
  }

  // ---- stage 4: chunked pipeline: proj, fc1.c0, fc2.c0, fc1.c1, ... (18KB chunks) ----
  short8 ao[3];
  #pragma unroll
  for (int s = 0; s < 3; ++s)
    ao[s] = *(const short8*)&pool[OFF_Q + qq * SR + 32 * s + 8 * gq];
  __syncthreads();   // all waves past attention -> X/K/V dead -> buffers usable

  // T14 completion: proj sets VGPR -> buf0 via LDS writes (no exposed global latency)
  if constexpr (PRE) {
    #pragma unroll
    for (int i = 0; i < 5; ++i) {
      int s = wv + 4 * i;
      if (s < 18) *(uint4*)(b0set(pool, s) + lane * 8) = pjreg[i];
    }
  }
  __syncthreads();

  // phase 0: stage fc1.c0 -> buf1 || proj from buf0 + residual + LN2 -> yn (OFF_Q row)
  if constexpr (PRE) stage18<true>(wsw + WFC1, pool, wv, lane);
  float y[6][4];
  __builtin_amdgcn_s_setprio(1);
  #pragma unroll
  for (int nt = 0; nt < 6; ++nt) {
    f32x4 acc = zf;
    #pragma unroll
    for (int s = 0; s < 3; ++s) {
      short8 wfr = PRE ? *(const short8*)(b0set(pool, nt * 3 + s) + lane * 8)
                       : ldw8(proj_w + (size_t)(16 * nt + ln) * 96 + 32 * s + 8 * gq);
      acc = __builtin_amdgcn_mfma_f32_16x16x32_bf16(wfr, ao[s], acc, 0, 0, 0);
    }
    float4 pb = *(const float4*)&proj_b[16 * nt + 4 * gq];
    y[nt][0] = acc[0] + pb.x + xraw[nt][0];
    y[nt][1] = acc[1] + pb.y + xraw[nt][1];
    y[nt][2] = acc[2] + pb.z + xraw[nt][2];
    y[nt][3] = acc[3] + pb.w + xraw[nt][3];
  }
  __builtin_amdgcn_s_setprio(0);
  {
    float s1 = 0.f, s2 = 0.f;
    #pragma unroll
    for (int nt = 0; nt < 6; ++nt)
      #pragma unroll
      for (int r = 0; r < 4; ++r) { s1 += y[nt][r]; s2 += y[nt][r] * y[nt][r]; }
    s1 += __shfl_xor(s1, 16, 64); s1 += __shfl_xor(s1, 32, 64);
    s2 += __shfl_xor(s2, 16, 64); s2 += __shfl_xor(s2, 32, 64);
    float mean = s1 * (1.f / 96.f);
    float inv  = rsqrtf(s2 * (1.f / 96.f) - mean * mean + 1e-5f);
    #pragma unroll
    for (int nt = 0; nt < 6; ++nt) {
      float4 g4 = *(const float4*)&n2g[16 * nt + 4 * gq];
      float4 b4 = *(const float4*)&n2b[16 * nt + 4 * gq];
      st4(&pool[OFF_Q + qq * SR + 16 * nt + 4 * gq],
          (y[nt][0] - mean) * inv * g4.x + b4.x,
          (y[nt][1] - mean) * inv * g4.y + b4.y,
          (y[nt][2] - mean) * inv * g4.z + b4.z,
          (y[nt][3] - mean) * inv * g4.w + b4.w);
    }
  }
  short8 ay[3];
  #pragma unroll
  for (int s = 0; s < 3; ++s)
    ay[s] = *(const short8*)&pool[OFF_Q + qq * SR + 32 * s + 8 * gq];
  __syncthreads();   // fc1.c0 landed in buf1; buf0 reads done; yn row now dead (h reuses it)

  // ---- MLP: 4 chunks x 2 phases; fc1 reads buf1, fc2 reads buf0; h via OFF_Q own row ----
  f32x4 accO[6] = {zf, zf, zf, zf, zf, zf};
  for (int cn = 0; cn < 4; ++cn) {
    // fc1 phase: stage fc2.cn -> buf0 || fc1.cn from buf1 -> gelu -> h (OFF_Q row) -> ah
    if constexpr (PRE) stage18<false>(wsw + WFC2 + (cn * 18) * 512, pool, wv, lane);
    __builtin_amdgcn_s_setprio(1);
    #pragma unroll
    for (int nt = 0; nt < 6; ++nt) {
      f32x4 acc = zf;
      #pragma unroll
      for (int s = 0; s < 3; ++s) {
        short8 wfr = PRE ? *(const short8*)(b1set(pool, nt * 3 + s) + lane * 8)
                         : ldw8(fc1_w + (size_t)(96 * cn + 16 * nt + ln) * 96 + 32 * s + 8 * gq);
        acc = __builtin_amdgcn_mfma_f32_16x16x32_bf16(wfr, ay[s], acc, 0, 0, 0);
      }
      float4 b1 = *(const float4*)&fc1_b[96 * cn + 16 * nt + 4 * gq];
      st4(&pool[OFF_Q + qq * SR + 16 * nt + 4 * gq],
          gelu(acc[0] + b1.x), gelu(acc[1] + b1.y),
          gelu(acc[2] + b1.z), gelu(acc[3] + b1.w));
    }
    __builtin_amdgcn_s_setprio(0);
    short8 ah[3];
    #pragma unroll
    for (int s = 0; s < 3; ++s)
      ah[s] = *(const short8*)&pool[OFF_Q + qq * SR + 32 * s + 8 * gq];
    __syncthreads();   // fc2.cn landed in buf0; buf1 reads done

    // fc2 phase: stage fc1.(cn+1) -> buf1 || fc2.cn from buf0 into accO
    if constexpr (PRE) { if (cn < 3) stage18<true>(wsw + WFC1 + ((cn + 1) * 18) * 512, pool, wv, lane); }
    __builtin_amdgcn_s_setprio(1);
    #pragma unroll
    for (int nt = 0; nt < 6; ++nt) {
      #pragma unroll
      for (int s = 0; s < 3; ++s) {
        short8 wfr = PRE ? *(const short8*)(b0set(pool, nt * 3 + s) + lane * 8)
                         : ldw8(fc2_w + (size_t)(16 * nt + ln) * 384 + 96 * cn + 32 * s + 8 * gq);
        accO[nt] = __builtin_amdgcn_mfma_f32_16x16x32_bf16(wfr, ah[s], accO[nt], 0, 0, 0);
      }
    }
    __builtin_amdgcn_s_setprio(0);
    if (cn < 3) __syncthreads();   // fc1.(cn+1) landed in buf1; buf0 reads done
  }

  // ---- stage 5: out = y + mlp + fc2_b (float4 stores) ----
  if (qq < 49) {
    float* dst = out + obase;
    #pragma unroll
    for (int nt = 0; nt < 6; ++nt) {
      float4 fb = *(const float4*)&fc2_b[16 * nt + 4 * gq];
      float4 v;
      v.x = y[nt][0] + accO[nt][0] + fb.x;
      v.y = y[nt][1] + accO[nt][1] + fb.y;
      v.z = y[nt][2] + accO[nt][2] + fb.z;
      v.w = y[nt][3] + accO[nt][3] + fb.w;
      *(float4*)&dst[16 * nt + 4 * gq] = v;
    }
  }
}

extern "C" void kernel_launch(void* const* d_in, const int* in_sizes, int n_in,
                              void* d_out, int out_size, void* d_ws, size_t ws_size,
                              hipStream_t stream) {
  const float* x         = (const float*)d_in[0];
  const float* attn_mask = (const float*)d_in[1];
  const int*   rel_index = (const int*)  d_in[2];
  const float* n1g       = (const float*)d_in[3];
  const float* n1b       = (const float*)d_in[4];
  const float* qkv_w     = (const float*)d_in[5];
  const float* qkv_b     = (const float*)d_in[6];
  const float* rel_tab   = (const float*)d_in[7];
  const float* proj_w    = (const float*)d_in[8];
  const float* proj_b    = (const float*)d_in[9];
  const float* n2g       = (const float*)d_in[10];
  const float* n2b       = (const float*)d_in[11];
  const float* fc1_w     = (const float*)d_in[12];
  const float* fc1_b     = (const float*)d_in[13];
  const float* fc2_w     = (const float*)d_in[14];
  const float* fc2_b     = (const float*)d_in[15];
  float* out = (float*)d_out;

  const int B = in_sizes[0] / (HW * HW * 96);
  const bool m1 = ws_size >= WS_M1;
  const bool m2 = ws_size >= WS_M2;
  short* ws    = (short*)d_ws;
  float* bias3 = (float*)((char*)d_ws + WS_M1);

  if (m1)
    cvt_weights<<<(WTOT + 255) / 256, 256, 0, stream>>>(qkv_w, proj_w, fc1_w, fc2_w, ws);
  if (m2)
    prep_bias<<<(BIASN + 255) / 256, 256, 0, stream>>>(attn_mask, rel_index, rel_tab, bias3);

  if (m2)
    swin_mfma_kernel<2><<<B * 64, 256, 0, stream>>>(
        x, attn_mask, rel_index, n1g, n1b, qkv_w, qkv_b, rel_tab, proj_w, proj_b,
        n2g, n2b, fc1_w, fc1_b, fc2_w, fc2_b, (const short*)ws, (const float*)bias3, out);
  else if (m1)
    swin_mfma_kernel<1><<<B * 64, 256, 0, stream>>>(
        x, attn_mask, rel_index, n1g, n1b, qkv_w, qkv_b, rel_tab, proj_w, proj_b,
        n2g, n2b, fc1_w, fc1_b, fc2_w, fc2_b, (const short*)ws, (const float*)nullptr, out);
  else
    swin_mfma_kernel<0><<<B * 64, 256, 0, stream>>>(
        x, attn_mask, rel_index, n1g, n1b, qkv_w, qkv_b, rel_tab, proj_w, proj_b,
        n2g, n2b, fc1_w, fc1_b, fc2_w, fc2_b, (const short*)nullptr, (const float*)nullptr, out);
}

// Round 18
// 151.802 us; speedup vs baseline: 1.1532x; 1.1532x over previous
//
#include <hip/hip_runtime.h>
#include <hip/hip_bf16.h>

// Swin block fully fused, bf16 MFMA. B=64, H=W=56, C=96, nh=3, d=32, WS=7, SS=3, N=49, nW=64.
// Round 18: restore round-15 verified best (152 us). Round-13 base + 18KB-chunk MLP pipeline
// (buf0 contiguous in K+V, buf1 scattered over X + K/V remainder), h via dead yn row.
typedef __attribute__((ext_vector_type(8))) short short8;  // 8 bf16 = one A/B frag
typedef __attribute__((ext_vector_type(4))) float f32x4;   // C/D frag

constexpr int HW = 56;

// ---- LDS pool (bf16 elements). Frag-read bases 16B-aligned. ----
constexpr int SR    = 104;             // row stride for [64][96] token-major buffers
constexpr int SVT   = 200;             // row stride for vT [32][3*64]
constexpr int OFF_X = 0;               // [64][SR]: xln -> P (own row) -> buf1 sets 0..12
constexpr int OFF_Q = 64 * SR;         // [64][SR]: q -> attn-out -> yn -> h (all own row)
constexpr int OFF_K = 2 * 64 * SR;     // [64][SR]: k ; after attention: buf0
constexpr int OFF_V = 3 * 64 * SR;     // [32][SVT]: v^T ; tail of buf0 + buf1 sets 13..17
constexpr int POOLN = OFF_V + 32 * SVT;  // 26368 shorts = 52736 B -> 3 blocks/CU
// post-attention weight buffers (set = 512 shorts):
//   buf0: sets 0..17 at OFF_K + s*512
//   buf1: sets 0..12 at s*512 (X region); sets 13..17 at 22528 + (s-13)*512

// ---- d_ws layout: bf16 weights frag-major [set*512 + lane*8 + j], then f32 bias planes ----
constexpr int WQKV  = 0;               // 18 tiles; Q tiles pre-scaled by d^-0.5
constexpr int WPROJ = 27648;           // 18 sets (one 18KB chunk)
constexpr int WFC1  = 36864;           // chunk-major: chunk cn = sets cn*18 .. cn*18+17
constexpr int WFC2  = 73728;           // chunk-major
constexpr int WTOT  = 110592;          // *2B = 221184 bytes
constexpr int BIASN = 64 * 3 * 49 * 64;           // f32 elements
constexpr size_t WS_M1 = (size_t)WTOT * 2;        // weights only
constexpr size_t WS_M2 = WS_M1 + (size_t)BIASN * 4;  // + bias planes

__device__ __forceinline__ ushort bfc(float f) {
  union { __hip_bfloat16 h; ushort u; } v;
  v.h = __float2bfloat16(f);
  return v.u;
}
__device__ __forceinline__ uint pk2(float a, float b) {
  union { __hip_bfloat162 h2; uint u; } v;
  v.h2 = __float22bfloat162_rn(make_float2(a, b));
  return v.u;
}
__device__ __forceinline__ void st4(short* p, float a, float b, float c, float d) {
  uint2 u; u.x = pk2(a, b); u.y = pk2(c, d);
  *(uint2*)p = u;
}
__device__ __forceinline__ short8 ldw8(const float* p) {
  float4 a = *(const float4*)p;
  float4 b = *(const float4*)(p + 4);
  short8 r;
  r[0] = (short)bfc(a.x); r[1] = (short)bfc(a.y); r[2] = (short)bfc(a.z); r[3] = (short)bfc(a.w);
  r[4] = (short)bfc(b.x); r[5] = (short)bfc(b.y); r[6] = (short)bfc(b.z); r[7] = (short)bfc(b.w);
  return r;
}
template<bool PRE>
__device__ __forceinline__ short8 wfrag(const short* wsb, int ts, int lane, const float* fsrc) {
  if constexpr (PRE) return *(const short8*)&wsb[(ts << 9) + lane * 8];
  else               return ldw8(fsrc);
}
// GELU sigmoid form with fast rcp: x * sigma(1.702 x)
__device__ __forceinline__ float gelu(float v) {
  return v * __builtin_amdgcn_rcpf(1.0f + __expf(-1.702f * v));
}
// buffer set bases
__device__ __forceinline__ short* b0set(short* pool, int s) {
  return pool + OFF_K + (s << 9);
}
__device__ __forceinline__ short* b1set(short* pool, int s) {
  return pool + (s < 13 ? (s << 9) : 22528 + ((s - 13) << 9));
}
// stage one 18KB chunk (18 sets) global->LDS, wave-split; B selects buf0/buf1
template<bool B1>
__device__ __forceinline__ void stage18(const short* g0, short* pool, int wv, int lane) {
  #pragma unroll
  for (int i = 0; i < 5; ++i) {
    int s = wv + 4 * i;
    if (s < 18) {
      short* dst = B1 ? b1set(pool, s) : b0set(pool, s);
      __builtin_amdgcn_global_load_lds((const unsigned int*)(g0 + (s << 9) + lane * 8),
                                       (unsigned int*)dst, 16, 0, 0);
    }
  }
}

// one-shot weight conversion f32 -> bf16, frag-major; Q tiles pre-scaled by d^-0.5
__global__ __launch_bounds__(256) void cvt_weights(
    const float* __restrict__ qkv_w, const float* __restrict__ proj_w,
    const float* __restrict__ fc1_w, const float* __restrict__ fc2_w,
    short* __restrict__ ws)
{
  int idx = blockIdx.x * 256 + threadIdx.x;
  if (idx >= WTOT) return;
  int j = idx & 7, lane = (idx >> 3) & 63;
  int cl = lane & 15;
  int g  = 8 * (lane >> 4) + j;
  float v;
  if (idx < WPROJ) {
    int ts = idx >> 9; int tile = ts / 3, s = ts - 3 * tile;
    v = qkv_w[(size_t)(16 * tile + cl) * 96 + 32 * s + g];
    if (tile < 6) v *= 0.17677669529663687f;   // fold Q scale
  } else if (idx < WFC1) {
    int ts = (idx - WPROJ) >> 9; int tile = ts / 3, s = ts - 3 * tile;
    v = proj_w[(size_t)(16 * tile + cl) * 96 + 32 * s + g];
  } else if (idx < WFC2) {
    int ts = (idx - WFC1) >> 9; int T = ts / 3, s = ts - 3 * T;
    int cn = T / 6, nt = T - 6 * cn;
    v = fc1_w[(size_t)(96 * cn + 16 * nt + cl) * 96 + 32 * s + g];
  } else {
    int ts = (idx - WFC2) >> 9; int T = ts / 3, s = ts - 3 * T;
    int cn = T / 6, nt = T - 6 * cn;
    v = fc2_w[(size_t)(16 * nt + cl) * 384 + 96 * cn + 32 * s + g];
  }
  ws[idx] = (short)bfc(v);
}

// one-shot fused bias planes: bias3[widx][h][q][64] = rel_bias + mask (k>=49 -> -1e30)
__global__ __launch_bounds__(256) void prep_bias(
    const float* __restrict__ attn_mask, const int* __restrict__ rel_index,
    const float* __restrict__ rel_tab, float* __restrict__ bias3)
{
  int idx = blockIdx.x * 256 + threadIdx.x;
  if (idx >= BIASN) return;
  int k = idx & 63;
  int t = idx >> 6;             // (widx*3 + h)*49 + q
  int q = t % 49;
  int wh = t / 49;
  int h = wh % 3, w = wh / 3;
  float v = -1e30f;
  if (k < 49) {
    int qk = q * 49 + k;
    v = rel_tab[rel_index[qk] * 3 + h] + attn_mask[(size_t)w * 2401 + qk];
  }
  bias3[idx] = v;
}

template<int MODE>   // 0: no ws; 1: +bf16 weights; 2: +bias planes
__global__ __launch_bounds__(256, 3) void swin_mfma_kernel(
    const float* __restrict__ x,          // [B,3136,96]
    const float* __restrict__ attn_mask,  // [64,49,49]
    const int*   __restrict__ rel_index,  // [2401]
    const float* __restrict__ n1g, const float* __restrict__ n1b,
    const float* __restrict__ qkv_w, const float* __restrict__ qkv_b,
    const float* __restrict__ rel_tab,    // [169,3]
    const float* __restrict__ proj_w, const float* __restrict__ proj_b,
    const float* __restrict__ n2g, const float* __restrict__ n2b,
    const float* __restrict__ fc1_w, const float* __restrict__ fc1_b,
    const float* __restrict__ fc2_w, const float* __restrict__ fc2_b,
    const short* __restrict__ wsw,
    const float* __restrict__ bias3,
    float* __restrict__ out)              // [B,3136,96]
{
  constexpr bool PRE = (MODE >= 1);
  __shared__ alignas(16) short pool[POOLN];

  const int tid  = threadIdx.x;
  const int wv   = tid >> 6;
  const int lane = tid & 63;
  const int ln   = lane & 15;
  const int gq   = lane >> 4;
  const int bw   = blockIdx.x;
  const int b    = bw >> 6, widx = bw & 63;
  const int wr   = widx >> 3, wc = widx & 7;

  const f32x4 zf = {0.f, 0.f, 0.f, 0.f};
  const int qq = 16 * wv + ln;        // this thread's token row

  auto gbase = [&](int n) -> size_t {
    int i = n / 7, j = n - 7 * i;
    int h = wr * 7 + i + 3; if (h >= HW) h -= HW;   // roll(-3)
    int w = wc * 7 + j + 3; if (w >= HW) w -= HW;
    return ((size_t)b * (HW * HW) + (size_t)h * HW + w) * 96;
  };
  const size_t obase = gbase(qq < 49 ? qq : 48);

  // ---- stage 1: token-per-thread-column load + LN1 -> xln; raw x kept in VGPRs ----
  float xraw[6][4];
  {
    if (qq < 49) {
      const float* xr = x + obase;
      #pragma unroll
      for (int nt = 0; nt < 6; ++nt) {
        float4 v = *(const float4*)&xr[16 * nt + 4 * gq];
        xraw[nt][0] = v.x; xraw[nt][1] = v.y; xraw[nt][2] = v.z; xraw[nt][3] = v.w;
      }
    } else {
      #pragma unroll
      for (int nt = 0; nt < 6; ++nt)
        xraw[nt][0] = xraw[nt][1] = xraw[nt][2] = xraw[nt][3] = 0.f;
    }
    float s1 = 0.f, s2 = 0.f;
    #pragma unroll
    for (int nt = 0; nt < 6; ++nt)
      #pragma unroll
      for (int r = 0; r < 4; ++r) { s1 += xraw[nt][r]; s2 += xraw[nt][r] * xraw[nt][r]; }
    s1 += __shfl_xor(s1, 16, 64); s1 += __shfl_xor(s1, 32, 64);
    s2 += __shfl_xor(s2, 16, 64); s2 += __shfl_xor(s2, 32, 64);
    float mean = s1 * (1.f / 96.f);
    float inv  = rsqrtf(s2 * (1.f / 96.f) - mean * mean + 1e-5f);
    #pragma unroll
    for (int nt = 0; nt < 6; ++nt) {
      float4 g4 = *(const float4*)&n1g[16 * nt + 4 * gq];
      float4 b4 = *(const float4*)&n1b[16 * nt + 4 * gq];
      st4(&pool[OFF_X + qq * SR + 16 * nt + 4 * gq],
          (xraw[nt][0] - mean) * inv * g4.x + b4.x,
          (xraw[nt][1] - mean) * inv * g4.y + b4.y,
          (xraw[nt][2] - mean) * inv * g4.z + b4.z,
          (xraw[nt][3] - mean) * inv * g4.w + b4.w);
    }
  }
  __syncthreads();

  // ---- stage 2: QKV. Q/K channel-rows; V transposed token-rows. N-split across waves ----
  {
    short8 af[3][4];
    #pragma unroll
    for (int s = 0; s < 3; ++s)
      #pragma unroll
      for (int m = 0; m < 4; ++m)
        af[s][m] = *(const short8*)&pool[OFF_X + (16 * m + ln) * SR + 32 * s + 8 * gq];

    const float sc_ = 0.17677669529663687f;
    for (int t = wv; t < 18; t += 4) {
      short8 wf[3];
      #pragma unroll
      for (int s = 0; s < 3; ++s)
        wf[s] = wfrag<PRE>(wsw + WQKV, t * 3 + s, lane,
                           qkv_w + (size_t)(16 * t + ln) * 96 + 32 * s + 8 * gq);
      int which = t / 6;               // 0=q 1=k 2=v
      if (which == 2) {
        int d  = 16 * (t - 12) + ln;
        float bv = qkv_b[192 + d];
        int dd = d & 31, hh = d >> 5;
        __builtin_amdgcn_s_setprio(1);
        #pragma unroll
        for (int m = 0; m < 4; ++m) {
          f32x4 acc = zf;
          #pragma unroll
          for (int s = 0; s < 3; ++s)
            acc = __builtin_amdgcn_mfma_f32_16x16x32_bf16(af[s][m], wf[s], acc, 0, 0, 0);
          st4(&pool[OFF_V + dd * SVT + hh * 64 + 16 * m + 4 * gq],
              acc[0] + bv, acc[1] + bv, acc[2] + bv, acc[3] + bv);
        }
        __builtin_amdgcn_s_setprio(0);
      } else {
        float4 b4 = *(const float4*)&qkv_b[16 * t + 4 * gq];
        if (which == 0) {
          if constexpr (PRE) { b4.x *= sc_; b4.y *= sc_; b4.z *= sc_; b4.w *= sc_; }
        }
        __builtin_amdgcn_s_setprio(1);
        #pragma unroll
        for (int m = 0; m < 4; ++m) {
          f32x4 acc = zf;
          #pragma unroll
          for (int s = 0; s < 3; ++s)
            acc = __builtin_amdgcn_mfma_f32_16x16x32_bf16(wf[s], af[s][m], acc, 0, 0, 0);
          int tok = 16 * m + ln;
          float v0 = acc[0] + b4.x, v1 = acc[1] + b4.y, v2 = acc[2] + b4.z, v3 = acc[3] + b4.w;
          if (which == 0) {
            if constexpr (PRE)
              st4(&pool[OFF_Q + tok * SR + 16 * t + 4 * gq], v0, v1, v2, v3);
            else
              st4(&pool[OFF_Q + tok * SR + 16 * t + 4 * gq], v0 * sc_, v1 * sc_, v2 * sc_, v3 * sc_);
          } else {
            st4(&pool[OFF_K + tok * SR + 16 * (t - 6) + 4 * gq], v0, v1, v2, v3);
          }
        }
        __builtin_amdgcn_s_setprio(0);
      }
    }
  }
  __syncthreads();

  // ---- stage 3: attention, per-head (bias+mask via C-in, no-max-sub softmax, rcp) ----
  const int qc = qq < 49 ? qq : 48;
  int   relvv[4][4];
  float maskb[4][4];
  if constexpr (MODE < 2) {
    #pragma unroll
    for (int nt = 0; nt < 4; ++nt)
      #pragma unroll
      for (int r = 0; r < 4; ++r) {
        int key = 16 * nt + 4 * gq + r;
        if (key < 49) {
          int qk = qc * 49 + key;
          relvv[nt][r] = rel_index[qk];
          maskb[nt][r] = attn_mask[(size_t)widx * 2401 + qk];
        } else {
          relvv[nt][r] = 0;
          maskb[nt][r] = -1e30f;
        }
      }
  }
  const float* bph = nullptr;
  if constexpr (MODE == 2) bph = bias3 + ((size_t)widx * 3 * 49 + qc) * 64;

  for (int h = 0; h < 3; ++h) {
    short8 bq = *(const short8*)&pool[OFF_Q + qq * SR + h * 32 + 8 * gq];
    f32x4 sc[4];
    __builtin_amdgcn_s_setprio(1);
    #pragma unroll
    for (int nt = 0; nt < 4; ++nt) {
      f32x4 bia;
      if constexpr (MODE == 2) {
        bia = *(const f32x4*)&bph[h * 3136 + 16 * nt + 4 * gq];
      } else {
        #pragma unroll
        for (int r = 0; r < 4; ++r)
          bia[r] = rel_tab[relvv[nt][r] * 3 + h] + maskb[nt][r];
      }
      short8 ak = *(const short8*)&pool[OFF_K + (16 * nt + ln) * SR + h * 32 + 8 * gq];
      sc[nt] = __builtin_amdgcn_mfma_f32_16x16x32_bf16(ak, bq, bia, 0, 0, 0);
    }
    __builtin_amdgcn_s_setprio(0);
    float pv[4][4];
    float sum = 0.f;
    #pragma unroll
    for (int nt = 0; nt < 4; ++nt)
      #pragma unroll
      for (int r = 0; r < 4; ++r) { pv[nt][r] = __expf(sc[nt][r]); sum += pv[nt][r]; }
    sum += __shfl_xor(sum, 16, 64);
    sum += __shfl_xor(sum, 32, 64);
    float inv = __builtin_amdgcn_rcpf(sum);
    #pragma unroll
    for (int nt = 0; nt < 4; ++nt)
      st4(&pool[OFF_X + qq * SR + 16 * nt + 4 * gq],
          pv[nt][0] * inv, pv[nt][1] * inv, pv[nt][2] * inv, pv[nt][3] * inv);

    short8 bp0 = *(const short8*)&pool[OFF_X + qq * SR + 8 * gq];
    short8 bp1 = *(const short8*)&pool[OFF_X + qq * SR + 32 + 8 * gq];
    __builtin_amdgcn_s_setprio(1);
    #pragma unroll
    for (int dt = 0; dt < 2; ++dt) {
      short8 av0 = *(const short8*)&pool[OFF_V + (16 * dt + ln) * SVT + h * 64 + 8 * gq];
      short8 av1 = *(const short8*)&pool[OFF_V + (16 * dt + ln) * SVT + h * 64 + 32 + 8 * gq];
      f32x4 o = __builtin_amdgcn_mfma_f32_16x16x32_bf16(av0, bp0, zf, 0, 0, 0);
      o = __builtin_amdgcn_mfma_f32_16x16x32_bf16(av1, bp1, o, 0, 0, 0);
      st4(&pool[OFF_Q + qq * SR + h * 32 + 16 * dt + 4 * gq], o[0], o[1], o[2], o[3]);
    }
    __builtin_amdgcn_s_setprio(0);
  }

  // ---- stage 4: chunked pipeline: proj, fc1.c0, fc2.c0, fc1.c1, ... (18KB chunks) ----
  short8 ao[3];
  #pragma unroll
  for (int s = 0; s < 3; ++s)
    ao[s] = *(const short8*)&pool[OFF_Q + qq * SR + 32 * s + 8 * gq];
  __syncthreads();   // all waves past attention -> X/K/V dead -> buffers usable

  if constexpr (PRE) stage18<false>(wsw + WPROJ, pool, wv, lane);  // proj -> buf0 (exposed once)
  __syncthreads();

  // phase 0: stage fc1.c0 -> buf1 || proj from buf0 + residual + LN2 -> yn (OFF_Q row)
  if constexpr (PRE) stage18<true>(wsw + WFC1, pool, wv, lane);
  float y[6][4];
  __builtin_amdgcn_s_setprio(1);
  #pragma unroll
  for (int nt = 0; nt < 6; ++nt) {
    f32x4 acc = zf;
    #pragma unroll
    for (int s = 0; s < 3; ++s) {
      short8 wfr = PRE ? *(const short8*)(b0set(pool, nt * 3 + s) + lane * 8)
                       : ldw8(proj_w + (size_t)(16 * nt + ln) * 96 + 32 * s + 8 * gq);
      acc = __builtin_amdgcn_mfma_f32_16x16x32_bf16(wfr, ao[s], acc, 0, 0, 0);
    }
    float4 pb = *(const float4*)&proj_b[16 * nt + 4 * gq];
    y[nt][0] = acc[0] + pb.x + xraw[nt][0];
    y[nt][1] = acc[1] + pb.y + xraw[nt][1];
    y[nt][2] = acc[2] + pb.z + xraw[nt][2];
    y[nt][3] = acc[3] + pb.w + xraw[nt][3];
  }
  __builtin_amdgcn_s_setprio(0);
  {
    float s1 = 0.f, s2 = 0.f;
    #pragma unroll
    for (int nt = 0; nt < 6; ++nt)
      #pragma unroll
      for (int r = 0; r < 4; ++r) { s1 += y[nt][r]; s2 += y[nt][r] * y[nt][r]; }
    s1 += __shfl_xor(s1, 16, 64); s1 += __shfl_xor(s1, 32, 64);
    s2 += __shfl_xor(s2, 16, 64); s2 += __shfl_xor(s2, 32, 64);
    float mean = s1 * (1.f / 96.f);
    float inv  = rsqrtf(s2 * (1.f / 96.f) - mean * mean + 1e-5f);
    #pragma unroll
    for (int nt = 0; nt < 6; ++nt) {
      float4 g4 = *(const float4*)&n2g[16 * nt + 4 * gq];
      float4 b4 = *(const float4*)&n2b[16 * nt + 4 * gq];
      st4(&pool[OFF_Q + qq * SR + 16 * nt + 4 * gq],
          (y[nt][0] - mean) * inv * g4.x + b4.x,
          (y[nt][1] - mean) * inv * g4.y + b4.y,
          (y[nt][2] - mean) * inv * g4.z + b4.z,
          (y[nt][3] - mean) * inv * g4.w + b4.w);
    }
  }
  short8 ay[3];
  #pragma unroll
  for (int s = 0; s < 3; ++s)
    ay[s] = *(const short8*)&pool[OFF_Q + qq * SR + 32 * s + 8 * gq];
  __syncthreads();   // fc1.c0 landed in buf1; buf0 reads done; yn row now dead (h reuses it)

  // ---- MLP: 4 chunks x 2 phases; fc1 reads buf1, fc2 reads buf0; h via OFF_Q own row ----
  f32x4 accO[6] = {zf, zf, zf, zf, zf, zf};
  for (int cn = 0; cn < 4; ++cn) {
    // fc1 phase: stage fc2.cn -> buf0 || fc1.cn from buf1 -> gelu -> h (OFF_Q row) -> ah
    if constexpr (PRE) stage18<false>(wsw + WFC2 + (cn * 18) * 512, pool, wv, lane);
    __builtin_amdgcn_s_setprio(1);
    #pragma unroll
    for (int nt = 0; nt < 6; ++nt) {
      f32x4 acc = zf;
      #pragma unroll
      for (int s = 0; s < 3; ++s) {
        short8 wfr = PRE ? *(const short8*)(b1set(pool, nt * 3 + s) + lane * 8)
                         : ldw8(fc1_w + (size_t)(96 * cn + 16 * nt + ln) * 96 + 32 * s + 8 * gq);
        acc = __builtin_amdgcn_mfma_f32_16x16x32_bf16(wfr, ay[s], acc, 0, 0, 0);
      }
      float4 b1 = *(const float4*)&fc1_b[96 * cn + 16 * nt + 4 * gq];
      st4(&pool[OFF_Q + qq * SR + 16 * nt + 4 * gq],
          gelu(acc[0] + b1.x), gelu(acc[1] + b1.y),
          gelu(acc[2] + b1.z), gelu(acc[3] + b1.w));
    }
    __builtin_amdgcn_s_setprio(0);
    short8 ah[3];
    #pragma unroll
    for (int s = 0; s < 3; ++s)
      ah[s] = *(const short8*)&pool[OFF_Q + qq * SR + 32 * s + 8 * gq];
    __syncthreads();   // fc2.cn landed in buf0; buf1 reads done

    // fc2 phase: stage fc1.(cn+1) -> buf1 || fc2.cn from buf0 into accO
    if constexpr (PRE) { if (cn < 3) stage18<true>(wsw + WFC1 + ((cn + 1) * 18) * 512, pool, wv, lane); }
    __builtin_amdgcn_s_setprio(1);
    #pragma unroll
    for (int nt = 0; nt < 6; ++nt) {
      #pragma unroll
      for (int s = 0; s < 3; ++s) {
        short8 wfr = PRE ? *(const short8*)(b0set(pool, nt * 3 + s) + lane * 8)
                         : ldw8(fc2_w + (size_t)(16 * nt + ln) * 384 + 96 * cn + 32 * s + 8 * gq);
        accO[nt] = __builtin_amdgcn_mfma_f32_16x16x32_bf16(wfr, ah[s], accO[nt], 0, 0, 0);
      }
    }
    __builtin_amdgcn_s_setprio(0);
    if (cn < 3) __syncthreads();   // fc1.(cn+1) landed in buf1; buf0 reads done
  }

  // ---- stage 5: out = y + mlp + fc2_b (float4 stores) ----
  if (qq < 49) {
    float* dst = out + obase;
    #pragma unroll
    for (int nt = 0; nt < 6; ++nt) {
      float4 fb = *(const float4*)&fc2_b[16 * nt + 4 * gq];
      float4 v;
      v.x = y[nt][0] + accO[nt][0] + fb.x;
      v.y = y[nt][1] + accO[nt][1] + fb.y;
      v.z = y[nt][2] + accO[nt][2] + fb.z;
      v.w = y[nt][3] + accO[nt][3] + fb.w;
      *(float4*)&dst[16 * nt + 4 * gq] = v;
    }
  }
}

extern "C" void kernel_launch(void* const* d_in, const int* in_sizes, int n_in,
                              void* d_out, int out_size, void* d_ws, size_t ws_size,
                              hipStream_t stream) {
  const float* x         = (const float*)d_in[0];
  const float* attn_mask = (const float*)d_in[1];
  const int*   rel_index = (const int*)  d_in[2];
  const float* n1g       = (const float*)d_in[3];
  const float* n1b       = (const float*)d_in[4];
  const float* qkv_w     = (const float*)d_in[5];
  const float* qkv_b     = (const float*)d_in[6];
  const float* rel_tab   = (const float*)d_in[7];
  const float* proj_w    = (const float*)d_in[8];
  const float* proj_b    = (const float*)d_in[9];
  const float* n2g       = (const float*)d_in[10];
  const float* n2b       = (const float*)d_in[11];
  const float* fc1_w     = (const float*)d_in[12];
  const float* fc1_b     = (const float*)d_in[13];
  const float* fc2_w     = (const float*)d_in[14];
  const float* fc2_b     = (const float*)d_in[15];
  float* out = (float*)d_out;

  const int B = in_sizes[0] / (HW * HW * 96);
  const bool m1 = ws_size >= WS_M1;
  const bool m2 = ws_size >= WS_M2;
  short* ws    = (short*)d_ws;
  float* bias3 = (float*)((char*)d_ws + WS_M1);

  if (m1)
    cvt_weights<<<(WTOT + 255) / 256, 256, 0, stream>>>(qkv_w, proj_w, fc1_w, fc2_w, ws);
  if (m2)
    prep_bias<<<(BIASN + 255) / 256, 256, 0, stream>>>(attn_mask, rel_index, rel_tab, bias3);

  if (m2)
    swin_mfma_kernel<2><<<B * 64, 256, 0, stream>>>(
        x, attn_mask, rel_index, n1g, n1b, qkv_w, qkv_b, rel_tab, proj_w, proj_b,
        n2g, n2b, fc1_w, fc1_b, fc2_w, fc2_b, (const short*)ws, (const float*)bias3, out);
  else if (m1)
    swin_mfma_kernel<1><<<B * 64, 256, 0, stream>>>(
        x, attn_mask, rel_index, n1g, n1b, qkv_w, qkv_b, rel_tab, proj_w, proj_b,
        n2g, n2b, fc1_w, fc1_b, fc2_w, fc2_b, (const short*)ws, (const float*)nullptr, out);
  else
    swin_mfma_kernel<0><<<B * 64, 256, 0, stream>>>(
        x, attn_mask, rel_index, n1g, n1b, qkv_w, qkv_b, rel_tab, proj_w, proj_b,
        n2g, n2b, fc1_w, fc1_b, fc2_w, fc2_b, (const short*)nullptr, (const float*)nullptr, out);
}

// Round 19
// 150.204 us; speedup vs baseline: 1.1655x; 1.0106x over previous
//
#include <hip/hip_runtime.h>
#include <hip/hip_bf16.h>

// Swin block fully fused, bf16 MFMA. B=64, H=W=56, C=96, nh=3, d=32, WS=7, SS=3, N=49, nW=64.
// Round 19: r18 base + merged prep kernel + exp2-domain softmax (log2e folded into Q-scale
// and bias planes; native v_exp) + deferred softmax normalization (scale PV outputs).
typedef __attribute__((ext_vector_type(8))) short short8;  // 8 bf16 = one A/B frag
typedef __attribute__((ext_vector_type(4))) float f32x4;   // C/D frag

constexpr int HW = 56;
#define LOG2E 1.4426950408889634f
#define QSC   (0.17677669529663687f * LOG2E)   // d^-0.5 * log2(e): scores in log2 domain

// ---- LDS pool (bf16 elements). Frag-read bases 16B-aligned. ----
constexpr int SR    = 104;             // row stride for [64][96] token-major buffers
constexpr int SVT   = 200;             // row stride for vT [32][3*64]
constexpr int OFF_X = 0;               // [64][SR]: xln -> P (own row) -> buf1 sets 0..12
constexpr int OFF_Q = 64 * SR;         // [64][SR]: q -> attn-out -> yn -> h (all own row)
constexpr int OFF_K = 2 * 64 * SR;     // [64][SR]: k ; after attention: buf0
constexpr int OFF_V = 3 * 64 * SR;     // [32][SVT]: v^T ; tail of buf0 + buf1 sets 13..17
constexpr int POOLN = OFF_V + 32 * SVT;  // 26368 shorts = 52736 B -> 3 blocks/CU
// post-attention weight buffers (set = 512 shorts):
//   buf0: sets 0..17 at OFF_K + s*512
//   buf1: sets 0..12 at s*512 (X region); sets 13..17 at 22528 + (s-13)*512

// ---- d_ws layout: bf16 weights frag-major [set*512 + lane*8 + j], then f32 bias planes ----
constexpr int WQKV  = 0;               // 18 tiles; Q tiles pre-scaled by QSC
constexpr int WPROJ = 27648;           // 18 sets (one 18KB chunk)
constexpr int WFC1  = 36864;           // chunk-major: chunk cn = sets cn*18 .. cn*18+17
constexpr int WFC2  = 73728;           // chunk-major
constexpr int WTOT  = 110592;          // *2B = 221184 bytes
constexpr int BIASN = 64 * 3 * 49 * 64;           // f32 elements (prescaled by log2e)
constexpr size_t WS_M1 = (size_t)WTOT * 2;        // weights only
constexpr size_t WS_M2 = WS_M1 + (size_t)BIASN * 4;  // + bias planes

__device__ __forceinline__ ushort bfc(float f) {
  union { __hip_bfloat16 h; ushort u; } v;
  v.h = __float2bfloat16(f);
  return v.u;
}
__device__ __forceinline__ uint pk2(float a, float b) {
  union { __hip_bfloat162 h2; uint u; } v;
  v.h2 = __float22bfloat162_rn(make_float2(a, b));
  return v.u;
}
__device__ __forceinline__ void st4(short* p, float a, float b, float c, float d) {
  uint2 u; u.x = pk2(a, b); u.y = pk2(c, d);
  *(uint2*)p = u;
}
__device__ __forceinline__ short8 ldw8(const float* p) {
  float4 a = *(const float4*)p;
  float4 b = *(const float4*)(p + 4);
  short8 r;
  r[0] = (short)bfc(a.x); r[1] = (short)bfc(a.y); r[2] = (short)bfc(a.z); r[3] = (short)bfc(a.w);
  r[4] = (short)bfc(b.x); r[5] = (short)bfc(b.y); r[6] = (short)bfc(b.z); r[7] = (short)bfc(b.w);
  return r;
}
template<bool PRE>
__device__ __forceinline__ short8 wfrag(const short* wsb, int ts, int lane, const float* fsrc) {
  if constexpr (PRE) return *(const short8*)&wsb[(ts << 9) + lane * 8];
  else               return ldw8(fsrc);
}
// GELU sigmoid form with fast rcp: x * sigma(1.702 x)
__device__ __forceinline__ float gelu(float v) {
  return v * __builtin_amdgcn_rcpf(1.0f + __expf(-1.702f * v));
}
// buffer set bases
__device__ __forceinline__ short* b0set(short* pool, int s) {
  return pool + OFF_K + (s << 9);
}
__device__ __forceinline__ short* b1set(short* pool, int s) {
  return pool + (s < 13 ? (s << 9) : 22528 + ((s - 13) << 9));
}
// stage one 18KB chunk (18 sets) global->LDS, wave-split; B selects buf0/buf1
template<bool B1>
__device__ __forceinline__ void stage18(const short* g0, short* pool, int wv, int lane) {
  #pragma unroll
  for (int i = 0; i < 5; ++i) {
    int s = wv + 4 * i;
    if (s < 18) {
      short* dst = B1 ? b1set(pool, s) : b0set(pool, s);
      __builtin_amdgcn_global_load_lds((const unsigned int*)(g0 + (s << 9) + lane * 8),
                                       (unsigned int*)dst, 16, 0, 0);
    }
  }
}

// merged one-shot prep: weight cvt (f32->bf16 frag-major, Q pre-scaled by QSC)
// + fused bias planes bias3[widx][h][q][64] = (rel_bias + mask) * log2e  (k>=49 -> -1e30)
__global__ __launch_bounds__(256) void prep_all(
    const float* __restrict__ qkv_w, const float* __restrict__ proj_w,
    const float* __restrict__ fc1_w, const float* __restrict__ fc2_w,
    const float* __restrict__ attn_mask, const int* __restrict__ rel_index,
    const float* __restrict__ rel_tab,
    short* __restrict__ ws, float* __restrict__ bias3, int total)
{
  int idx = blockIdx.x * 256 + threadIdx.x;
  if (idx >= total) return;
  if (idx < WTOT) {
    int j = idx & 7, lane = (idx >> 3) & 63;
    int cl = lane & 15;
    int g  = 8 * (lane >> 4) + j;
    float v;
    if (idx < WPROJ) {
      int ts = idx >> 9; int tile = ts / 3, s = ts - 3 * tile;
      v = qkv_w[(size_t)(16 * tile + cl) * 96 + 32 * s + g];
      if (tile < 6) v *= QSC;   // fold Q scale + log2e
    } else if (idx < WFC1) {
      int ts = (idx - WPROJ) >> 9; int tile = ts / 3, s = ts - 3 * tile;
      v = proj_w[(size_t)(16 * tile + cl) * 96 + 32 * s + g];
    } else if (idx < WFC2) {
      int ts = (idx - WFC1) >> 9; int T = ts / 3, s = ts - 3 * T;
      int cn = T / 6, nt = T - 6 * cn;
      v = fc1_w[(size_t)(96 * cn + 16 * nt + cl) * 96 + 32 * s + g];
    } else {
      int ts = (idx - WFC2) >> 9; int T = ts / 3, s = ts - 3 * T;
      int cn = T / 6, nt = T - 6 * cn;
      v = fc2_w[(size_t)(16 * nt + cl) * 384 + 96 * cn + 32 * s + g];
    }
    ws[idx] = (short)bfc(v);
  } else {
    int bi = idx - WTOT;
    int k = bi & 63;
    int t = bi >> 6;              // (widx*3 + h)*49 + q
    int q = t % 49;
    int wh = t / 49;
    int h = wh % 3, w = wh / 3;
    float v = -1e30f;
    if (k < 49) {
      int qk = q * 49 + k;
      v = (rel_tab[rel_index[qk] * 3 + h] + attn_mask[(size_t)w * 2401 + qk]) * LOG2E;
    }
    bias3[bi] = v;
  }
}

template<int MODE>   // 0: no ws; 1: +bf16 weights; 2: +bias planes
__global__ __launch_bounds__(256, 3) void swin_mfma_kernel(
    const float* __restrict__ x,          // [B,3136,96]
    const float* __restrict__ attn_mask,  // [64,49,49]
    const int*   __restrict__ rel_index,  // [2401]
    const float* __restrict__ n1g, const float* __restrict__ n1b,
    const float* __restrict__ qkv_w, const float* __restrict__ qkv_b,
    const float* __restrict__ rel_tab,    // [169,3]
    const float* __restrict__ proj_w, const float* __restrict__ proj_b,
    const float* __restrict__ n2g, const float* __restrict__ n2b,
    const float* __restrict__ fc1_w, const float* __restrict__ fc1_b,
    const float* __restrict__ fc2_w, const float* __restrict__ fc2_b,
    const short* __restrict__ wsw,
    const float* __restrict__ bias3,
    float* __restrict__ out)              // [B,3136,96]
{
  constexpr bool PRE = (MODE >= 1);
  __shared__ alignas(16) short pool[POOLN];

  const int tid  = threadIdx.x;
  const int wv   = tid >> 6;
  const int lane = tid & 63;
  const int ln   = lane & 15;
  const int gq   = lane >> 4;
  const int bw   = blockIdx.x;
  const int b    = bw >> 6, widx = bw & 63;
  const int wr   = widx >> 3, wc = widx & 7;

  const f32x4 zf = {0.f, 0.f, 0.f, 0.f};
  const int qq = 16 * wv + ln;        // this thread's token row

  auto gbase = [&](int n) -> size_t {
    int i = n / 7, j = n - 7 * i;
    int h = wr * 7 + i + 3; if (h >= HW) h -= HW;   // roll(-3)
    int w = wc * 7 + j + 3; if (w >= HW) w -= HW;
    return ((size_t)b * (HW * HW) + (size_t)h * HW + w) * 96;
  };
  const size_t obase = gbase(qq < 49 ? qq : 48);

  // ---- stage 1: token-per-thread-column load + LN1 -> xln; raw x kept in VGPRs ----
  float xraw[6][4];
  {
    if (qq < 49) {
      const float* xr = x + obase;
      #pragma unroll
      for (int nt = 0; nt < 6; ++nt) {
        float4 v = *(const float4*)&xr[16 * nt + 4 * gq];
        xraw[nt][0] = v.x; xraw[nt][1] = v.y; xraw[nt][2] = v.z; xraw[nt][3] = v.w;
      }
    } else {
      #pragma unroll
      for (int nt = 0; nt < 6; ++nt)
        xraw[nt][0] = xraw[nt][1] = xraw[nt][2] = xraw[nt][3] = 0.f;
    }
    float s1 = 0.f, s2 = 0.f;
    #pragma unroll
    for (int nt = 0; nt < 6; ++nt)
      #pragma unroll
      for (int r = 0; r < 4; ++r) { s1 += xraw[nt][r]; s2 += xraw[nt][r] * xraw[nt][r]; }
    s1 += __shfl_xor(s1, 16, 64); s1 += __shfl_xor(s1, 32, 64);
    s2 += __shfl_xor(s2, 16, 64); s2 += __shfl_xor(s2, 32, 64);
    float mean = s1 * (1.f / 96.f);
    float inv  = rsqrtf(s2 * (1.f / 96.f) - mean * mean + 1e-5f);
    #pragma unroll
    for (int nt = 0; nt < 6; ++nt) {
      float4 g4 = *(const float4*)&n1g[16 * nt + 4 * gq];
      float4 b4 = *(const float4*)&n1b[16 * nt + 4 * gq];
      st4(&pool[OFF_X + qq * SR + 16 * nt + 4 * gq],
          (xraw[nt][0] - mean) * inv * g4.x + b4.x,
          (xraw[nt][1] - mean) * inv * g4.y + b4.y,
          (xraw[nt][2] - mean) * inv * g4.z + b4.z,
          (xraw[nt][3] - mean) * inv * g4.w + b4.w);
    }
  }
  __syncthreads();

  // ---- stage 2: QKV. Q/K channel-rows; V transposed token-rows. N-split across waves ----
  {
    short8 af[3][4];
    #pragma unroll
    for (int s = 0; s < 3; ++s)
      #pragma unroll
      for (int m = 0; m < 4; ++m)
        af[s][m] = *(const short8*)&pool[OFF_X + (16 * m + ln) * SR + 32 * s + 8 * gq];

    for (int t = wv; t < 18; t += 4) {
      short8 wf[3];
      #pragma unroll
      for (int s = 0; s < 3; ++s)
        wf[s] = wfrag<PRE>(wsw + WQKV, t * 3 + s, lane,
                           qkv_w + (size_t)(16 * t + ln) * 96 + 32 * s + 8 * gq);
      int which = t / 6;               // 0=q 1=k 2=v
      if (which == 2) {
        int d  = 16 * (t - 12) + ln;
        float bv = qkv_b[192 + d];
        int dd = d & 31, hh = d >> 5;
        __builtin_amdgcn_s_setprio(1);
        #pragma unroll
        for (int m = 0; m < 4; ++m) {
          f32x4 acc = zf;
          #pragma unroll
          for (int s = 0; s < 3; ++s)
            acc = __builtin_amdgcn_mfma_f32_16x16x32_bf16(af[s][m], wf[s], acc, 0, 0, 0);
          st4(&pool[OFF_V + dd * SVT + hh * 64 + 16 * m + 4 * gq],
              acc[0] + bv, acc[1] + bv, acc[2] + bv, acc[3] + bv);
        }
        __builtin_amdgcn_s_setprio(0);
      } else {
        float4 b4 = *(const float4*)&qkv_b[16 * t + 4 * gq];
        if (which == 0) {
          if constexpr (PRE) { b4.x *= QSC; b4.y *= QSC; b4.z *= QSC; b4.w *= QSC; }
        }
        __builtin_amdgcn_s_setprio(1);
        #pragma unroll
        for (int m = 0; m < 4; ++m) {
          f32x4 acc = zf;
          #pragma unroll
          for (int s = 0; s < 3; ++s)
            acc = __builtin_amdgcn_mfma_f32_16x16x32_bf16(wf[s], af[s][m], acc, 0, 0, 0);
          int tok = 16 * m + ln;
          float v0 = acc[0] + b4.x, v1 = acc[1] + b4.y, v2 = acc[2] + b4.z, v3 = acc[3] + b4.w;
          if (which == 0) {
            if constexpr (PRE)
              st4(&pool[OFF_Q + tok * SR + 16 * t + 4 * gq], v0, v1, v2, v3);
            else
              st4(&pool[OFF_Q + tok * SR + 16 * t + 4 * gq], v0 * QSC, v1 * QSC, v2 * QSC, v3 * QSC);
          } else {
            st4(&pool[OFF_K + tok * SR + 16 * (t - 6) + 4 * gq], v0, v1, v2, v3);
          }
        }
        __builtin_amdgcn_s_setprio(0);
      }
    }
  }
  __syncthreads();

  // ---- stage 3: attention, per-head; scores in log2 domain; exp2 softmax with
  //      deferred normalization (scale PV outputs). P/AO own-row, no barriers. ----
  const int qc = qq < 49 ? qq : 48;
  int   relvv[4][4];
  float maskb[4][4];
  if constexpr (MODE < 2) {
    #pragma unroll
    for (int nt = 0; nt < 4; ++nt)
      #pragma unroll
      for (int r = 0; r < 4; ++r) {
        int key = 16 * nt + 4 * gq + r;
        if (key < 49) {
          int qk = qc * 49 + key;
          relvv[nt][r] = rel_index[qk];
          maskb[nt][r] = attn_mask[(size_t)widx * 2401 + qk];
        } else {
          relvv[nt][r] = 0;
          maskb[nt][r] = -1e30f;
        }
      }
  }
  const float* bph = nullptr;
  if constexpr (MODE == 2) bph = bias3 + ((size_t)widx * 3 * 49 + qc) * 64;

  for (int h = 0; h < 3; ++h) {
    short8 bq = *(const short8*)&pool[OFF_Q + qq * SR + h * 32 + 8 * gq];
    f32x4 sc[4];
    __builtin_amdgcn_s_setprio(1);
    #pragma unroll
    for (int nt = 0; nt < 4; ++nt) {
      f32x4 bia;
      if constexpr (MODE == 2) {
        bia = *(const f32x4*)&bph[h * 3136 + 16 * nt + 4 * gq];
      } else {
        #pragma unroll
        for (int r = 0; r < 4; ++r)
          bia[r] = (rel_tab[relvv[nt][r] * 3 + h] + maskb[nt][r]) * LOG2E;
      }
      short8 ak = *(const short8*)&pool[OFF_K + (16 * nt + ln) * SR + h * 32 + 8 * gq];
      sc[nt] = __builtin_amdgcn_mfma_f32_16x16x32_bf16(ak, bq, bia, 0, 0, 0);
    }
    __builtin_amdgcn_s_setprio(0);
    float pv[4][4];
    float sum = 0.f;
    #pragma unroll
    for (int nt = 0; nt < 4; ++nt)
      #pragma unroll
      for (int r = 0; r < 4; ++r) { pv[nt][r] = exp2f(sc[nt][r]); sum += pv[nt][r]; }
    // store UNNORMALIZED P immediately (LDS write no longer waits on the reduction)
    #pragma unroll
    for (int nt = 0; nt < 4; ++nt)
      st4(&pool[OFF_X + qq * SR + 16 * nt + 4 * gq],
          pv[nt][0], pv[nt][1], pv[nt][2], pv[nt][3]);
    sum += __shfl_xor(sum, 16, 64);
    sum += __shfl_xor(sum, 32, 64);
    float inv = __builtin_amdgcn_rcpf(sum);

    short8 bp0 = *(const short8*)&pool[OFF_X + qq * SR + 8 * gq];
    short8 bp1 = *(const short8*)&pool[OFF_X + qq * SR + 32 + 8 * gq];
    __builtin_amdgcn_s_setprio(1);
    #pragma unroll
    for (int dt = 0; dt < 2; ++dt) {
      short8 av0 = *(const short8*)&pool[OFF_V + (16 * dt + ln) * SVT + h * 64 + 8 * gq];
      short8 av1 = *(const short8*)&pool[OFF_V + (16 * dt + ln) * SVT + h * 64 + 32 + 8 * gq];
      f32x4 o = __builtin_amdgcn_mfma_f32_16x16x32_bf16(av0, bp0, zf, 0, 0, 0);
      o = __builtin_amdgcn_mfma_f32_16x16x32_bf16(av1, bp1, o, 0, 0, 0);
      st4(&pool[OFF_Q + qq * SR + h * 32 + 16 * dt + 4 * gq],
          o[0] * inv, o[1] * inv, o[2] * inv, o[3] * inv);   // deferred normalization
    }
    __builtin_amdgcn_s_setprio(0);
  }

  // ---- stage 4: chunked pipeline: proj, fc1.c0, fc2.c0, fc1.c1, ... (18KB chunks) ----
  short8 ao[3];
  #pragma unroll
  for (int s = 0; s < 3; ++s)
    ao[s] = *(const short8*)&pool[OFF_Q + qq * SR + 32 * s + 8 * gq];
  __syncthreads();   // all waves past attention -> X/K/V dead -> buffers usable

  if constexpr (PRE) stage18<false>(wsw + WPROJ, pool, wv, lane);  // proj -> buf0 (exposed once)
  __syncthreads();

  // phase 0: stage fc1.c0 -> buf1 || proj from buf0 + residual + LN2 -> yn (OFF_Q row)
  if constexpr (PRE) stage18<true>(wsw + WFC1, pool, wv, lane);
  float y[6][4];
  __builtin_amdgcn_s_setprio(1);
  #pragma unroll
  for (int nt = 0; nt < 6; ++nt) {
    f32x4 acc = zf;
    #pragma unroll
    for (int s = 0; s < 3; ++s) {
      short8 wfr = PRE ? *(const short8*)(b0set(pool, nt * 3 + s) + lane * 8)
                       : ldw8(proj_w + (size_t)(16 * nt + ln) * 96 + 32 * s + 8 * gq);
      acc = __builtin_amdgcn_mfma_f32_16x16x32_bf16(wfr, ao[s], acc, 0, 0, 0);
    }
    float4 pb = *(const float4*)&proj_b[16 * nt + 4 * gq];
    y[nt][0] = acc[0] + pb.x + xraw[nt][0];
    y[nt][1] = acc[1] + pb.y + xraw[nt][1];
    y[nt][2] = acc[2] + pb.z + xraw[nt][2];
    y[nt][3] = acc[3] + pb.w + xraw[nt][3];
  }
  __builtin_amdgcn_s_setprio(0);
  {
    float s1 = 0.f, s2 = 0.f;
    #pragma unroll
    for (int nt = 0; nt < 6; ++nt)
      #pragma unroll
      for (int r = 0; r < 4; ++r) { s1 += y[nt][r]; s2 += y[nt][r] * y[nt][r]; }
    s1 += __shfl_xor(s1, 16, 64); s1 += __shfl_xor(s1, 32, 64);
    s2 += __shfl_xor(s2, 16, 64); s2 += __shfl_xor(s2, 32, 64);
    float mean = s1 * (1.f / 96.f);
    float inv  = rsqrtf(s2 * (1.f / 96.f) - mean * mean + 1e-5f);
    #pragma unroll
    for (int nt = 0; nt < 6; ++nt) {
      float4 g4 = *(const float4*)&n2g[16 * nt + 4 * gq];
      float4 b4 = *(const float4*)&n2b[16 * nt + 4 * gq];
      st4(&pool[OFF_Q + qq * SR + 16 * nt + 4 * gq],
          (y[nt][0] - mean) * inv * g4.x + b4.x,
          (y[nt][1] - mean) * inv * g4.y + b4.y,
          (y[nt][2] - mean) * inv * g4.z + b4.z,
          (y[nt][3] - mean) * inv * g4.w + b4.w);
    }
  }
  short8 ay[3];
  #pragma unroll
  for (int s = 0; s < 3; ++s)
    ay[s] = *(const short8*)&pool[OFF_Q + qq * SR + 32 * s + 8 * gq];
  __syncthreads();   // fc1.c0 landed in buf1; buf0 reads done; yn row now dead (h reuses it)

  // ---- MLP: 4 chunks x 2 phases; fc1 reads buf1, fc2 reads buf0; h via OFF_Q own row ----
  f32x4 accO[6] = {zf, zf, zf, zf, zf, zf};
  for (int cn = 0; cn < 4; ++cn) {
    // fc1 phase: stage fc2.cn -> buf0 || fc1.cn from buf1 -> gelu -> h (OFF_Q row) -> ah
    if constexpr (PRE) stage18<false>(wsw + WFC2 + (cn * 18) * 512, pool, wv, lane);
    __builtin_amdgcn_s_setprio(1);
    #pragma unroll
    for (int nt = 0; nt < 6; ++nt) {
      f32x4 acc = zf;
      #pragma unroll
      for (int s = 0; s < 3; ++s) {
        short8 wfr = PRE ? *(const short8*)(b1set(pool, nt * 3 + s) + lane * 8)
                         : ldw8(fc1_w + (size_t)(96 * cn + 16 * nt + ln) * 96 + 32 * s + 8 * gq);
        acc = __builtin_amdgcn_mfma_f32_16x16x32_bf16(wfr, ay[s], acc, 0, 0, 0);
      }
      float4 b1 = *(const float4*)&fc1_b[96 * cn + 16 * nt + 4 * gq];
      st4(&pool[OFF_Q + qq * SR + 16 * nt + 4 * gq],
          gelu(acc[0] + b1.x), gelu(acc[1] + b1.y),
          gelu(acc[2] + b1.z), gelu(acc[3] + b1.w));
    }
    __builtin_amdgcn_s_setprio(0);
    short8 ah[3];
    #pragma unroll
    for (int s = 0; s < 3; ++s)
      ah[s] = *(const short8*)&pool[OFF_Q + qq * SR + 32 * s + 8 * gq];
    __syncthreads();   // fc2.cn landed in buf0; buf1 reads done

    // fc2 phase: stage fc1.(cn+1) -> buf1 || fc2.cn from buf0 into accO
    if constexpr (PRE) { if (cn < 3) stage18<true>(wsw + WFC1 + ((cn + 1) * 18) * 512, pool, wv, lane); }
    __builtin_amdgcn_s_setprio(1);
    #pragma unroll
    for (int nt = 0; nt < 6; ++nt) {
      #pragma unroll
      for (int s = 0; s < 3; ++s) {
        short8 wfr = PRE ? *(const short8*)(b0set(pool, nt * 3 + s) + lane * 8)
                         : ldw8(fc2_w + (size_t)(16 * nt + ln) * 384 + 96 * cn + 32 * s + 8 * gq);
        accO[nt] = __builtin_amdgcn_mfma_f32_16x16x32_bf16(wfr, ah[s], accO[nt], 0, 0, 0);
      }
    }
    __builtin_amdgcn_s_setprio(0);
    if (cn < 3) __syncthreads();   // fc1.(cn+1) landed in buf1; buf0 reads done
  }

  // ---- stage 5: out = y + mlp + fc2_b (float4 stores) ----
  if (qq < 49) {
    float* dst = out + obase;
    #pragma unroll
    for (int nt = 0; nt < 6; ++nt) {
      float4 fb = *(const float4*)&fc2_b[16 * nt + 4 * gq];
      float4 v;
      v.x = y[nt][0] + accO[nt][0] + fb.x;
      v.y = y[nt][1] + accO[nt][1] + fb.y;
      v.z = y[nt][2] + accO[nt][2] + fb.z;
      v.w = y[nt][3] + accO[nt][3] + fb.w;
      *(float4*)&dst[16 * nt + 4 * gq] = v;
    }
  }
}

extern "C" void kernel_launch(void* const* d_in, const int* in_sizes, int n_in,
                              void* d_out, int out_size, void* d_ws, size_t ws_size,
                              hipStream_t stream) {
  const float* x         = (const float*)d_in[0];
  const float* attn_mask = (const float*)d_in[1];
  const int*   rel_index = (const int*)  d_in[2];
  const float* n1g       = (const float*)d_in[3];
  const float* n1b       = (const float*)d_in[4];
  const float* qkv_w     = (const float*)d_in[5];
  const float* qkv_b     = (const float*)d_in[6];
  const float* rel_tab   = (const float*)d_in[7];
  const float* proj_w    = (const float*)d_in[8];
  const float* proj_b    = (const float*)d_in[9];
  const float* n2g       = (const float*)d_in[10];
  const float* n2b       = (const float*)d_in[11];
  const float* fc1_w     = (const float*)d_in[12];
  const float* fc1_b     = (const float*)d_in[13];
  const float* fc2_w     = (const float*)d_in[14];
  const float* fc2_b     = (const float*)d_in[15];
  float* out = (float*)d_out;

  const int B = in_sizes[0] / (HW * HW * 96);
  const bool m1 = ws_size >= WS_M1;
  const bool m2 = ws_size >= WS_M2;
  short* ws    = (short*)d_ws;
  float* bias3 = (float*)((char*)d_ws + WS_M1);

  if (m1) {
    const int total = m2 ? WTOT + BIASN : WTOT;
    prep_all<<<(total + 255) / 256, 256, 0, stream>>>(
        qkv_w, proj_w, fc1_w, fc2_w, attn_mask, rel_index, rel_tab, ws, bias3, total);
  }

  if (m2)
    swin_mfma_kernel<2><<<B * 64, 256, 0, stream>>>(
        x, attn_mask, rel_index, n1g, n1b, qkv_w, qkv_b, rel_tab, proj_w, proj_b,
        n2g, n2b, fc1_w, fc1_b, fc2_w, fc2_b, (const short*)ws, (const float*)bias3, out);
  else if (m1)
    swin_mfma_kernel<1><<<B * 64, 256, 0, stream>>>(
        x, attn_mask, rel_index, n1g, n1b, qkv_w, qkv_b, rel_tab, proj_w, proj_b,
        n2g, n2b, fc1_w, fc1_b, fc2_w, fc2_b, (const short*)ws, (const float*)nullptr, out);
  else
    swin_mfma_kernel<0><<<B * 64, 256, 0, stream>>>(
        x, attn_mask, rel_index, n1g, n1b, qkv_w, qkv_b, rel_tab, proj_w, proj_b,
        n2g, n2b, fc1_w, fc1_b, fc2_w, fc2_b, (const short*)nullptr, (const float*)nullptr, out);
}